// Round 5
// baseline (70.171 us; speedup 1.0000x reference)
//
#include <hip/hip_runtime.h>

// Fixed-shape problem
#define NBATCH 4
#define NPTS   8192
#define MTGT   8192
#define BN     (NBATCH*NPTS)      // 32768 sources
#define TPB    256
#define SPT    4                  // sources per thread
#define SPB    (TPB*SPT)          // 1024 sources per block
#define NXBLK  (BN/SPB)           // 32
#define CHUNK  128                // targets staged per block
#define NCHUNK (MTGT/CHUNK)       // 64  -> grid 32x64 = 2048 blocks (8/CU)

// Monotone float->uint key: preserves float ordering under unsigned compare.
// atomicMin on keys is commutative/idempotent -> bit-deterministic result
// regardless of schedule (this combine scheme passed post-timing in R1/R2).
__device__ __forceinline__ unsigned f2key(float x) {
    unsigned u = __float_as_uint(x);
    return (u & 0x80000000u) ? ~u : (u | 0x80000000u);
}
__device__ __forceinline__ float key2f(unsigned k) {
    return __uint_as_float((k & 0x80000000u) ? (k ^ 0x80000000u) : ~k);
}

__global__ __launch_bounds__(256) void init_kernel(unsigned* __restrict__ wsmin) {
    int i = blockIdx.x * 256 + threadIdx.x;
    wsmin[i] = 0xFFFFFFFFu;   // +inf in key space
}

// Per source point, min over one chunk of targets of d' = ||t||^2 - 2 s.t
// (exact sq distance = d' + ||s||^2, added in reduce)
__global__ __launch_bounds__(TPB) void nn_min_kernel(const float* __restrict__ src,
                                                     const float* __restrict__ tgt,
                                                     unsigned* __restrict__ wsmin) {
    __shared__ float  raw[CHUNK * 3];
    __shared__ float4 lt[CHUNK];     // (x,y,z,||t||^2); invalid -> 1e30

    const int tid = threadIdx.x;
    const int bx  = blockIdx.x;
    const int c   = blockIdx.y;
    const int b   = bx / (NPTS / SPB);   // 8 x-blocks per batch

    // ---- stage CHUNK targets (1536 B) ----
    const float4* tv = reinterpret_cast<const float4*>(
        tgt + ((size_t)b * MTGT + (size_t)c * CHUNK) * 3);
    if (tid < CHUNK * 3 / 4) reinterpret_cast<float4*>(raw)[tid] = tv[tid];
    __syncthreads();
    if (tid < CHUNK) {
        float x = raw[3 * tid], y = raw[3 * tid + 1], z = raw[3 * tid + 2];
        float tsq = fmaf(x, x, fmaf(y, y, z * z));
        bool valid = (x != 0.f) || (y != 0.f) || (z != 0.f);
        lt[tid] = make_float4(x, y, z, valid ? tsq : 1e30f);
    }
    __syncthreads();

    // ---- 4 source points: 3 contiguous float4 = 48 B per thread ----
    const int s0 = bx * SPB + tid * SPT;
    const float4* sv = reinterpret_cast<const float4*>(src + (size_t)s0 * 3);
    float4 q0 = sv[0], q1 = sv[1], q2 = sv[2];
    float sxs[4] = {q0.x, q0.w, q1.z, q2.y};
    float sys[4] = {q0.y, q1.x, q1.w, q2.z};
    float szs[4] = {q0.z, q1.y, q2.x, q2.w};

    float ax[4], ay[4], az[4], bm[4];
#pragma unroll
    for (int j = 0; j < 4; ++j) {
        ax[j] = -2.f * sxs[j];
        ay[j] = -2.f * sys[j];
        az[j] = -2.f * szs[j];
        bm[j] = 3e38f;
    }

    // ---- inner loop: register double-buffer hides ds_read latency;
    //      fminf(bm, fminf(d0,d1)) fusable to v_min3_f32 ----
    float4 t0 = lt[0], t1 = lt[1];
#pragma unroll 1
    for (int m = 0; m < CHUNK - 2; m += 2) {
        float4 n0 = lt[m + 2], n1 = lt[m + 3];   // prefetch next pair
#pragma unroll
        for (int j = 0; j < 4; ++j) {
            float d0 = fmaf(ax[j], t0.x, fmaf(ay[j], t0.y, fmaf(az[j], t0.z, t0.w)));
            float d1 = fmaf(ax[j], t1.x, fmaf(ay[j], t1.y, fmaf(az[j], t1.z, t1.w)));
            bm[j] = fminf(bm[j], fminf(d0, d1));
        }
        t0 = n0; t1 = n1;
    }
#pragma unroll
    for (int j = 0; j < 4; ++j) {   // tail pair
        float d0 = fmaf(ax[j], t0.x, fmaf(ay[j], t0.y, fmaf(az[j], t0.z, t0.w)));
        float d1 = fmaf(ax[j], t1.x, fmaf(ay[j], t1.y, fmaf(az[j], t1.z, t1.w)));
        bm[j] = fminf(bm[j], fminf(d0, d1));
    }

    // ---- combine: stale-check + atomicMin (stale >= true current -> safe skip) ----
    volatile unsigned* wv = wsmin;
#pragma unroll
    for (int j = 0; j < 4; ++j) {
        unsigned k = f2key(bm[j]);
        if (k < wv[s0 + j]) atomicMin(&wsmin[s0 + j], k);
    }
}

// 32 blocks: (batch, slice-of-1024-sources). Deterministic double partials.
__global__ __launch_bounds__(256) void reduce_kernel(const float* __restrict__ src,
                                                     const unsigned* __restrict__ wsmin,
                                                     double* __restrict__ partials) {
    const int blk = blockIdx.x;          // 0..31
    const int b = blk >> 3, slice = blk & 7;
    const int tid = threadIdx.x;

    double sum = 0.0, cnt = 0.0;
#pragma unroll
    for (int k = 0; k < 4; ++k) {
        int gid = b * NPTS + slice * 1024 + k * 256 + tid;
        float sx = src[(size_t)gid * 3 + 0];
        float sy = src[(size_t)gid * 3 + 1];
        float sz = src[(size_t)gid * 3 + 2];
        bool valid = (sx != 0.f) || (sy != 0.f) || (sz != 0.f);
        float ssq = fmaf(sx, sx, fmaf(sy, sy, sz * sz));
        float sq = fmaxf(0.f, ssq + key2f(wsmin[gid]));
        if (valid) { sum += (double)sq; cnt += 1.0; }
    }

    __shared__ double sh[512];
    sh[tid] = sum; sh[256 + tid] = cnt;
    __syncthreads();
    for (int s = 128; s > 0; s >>= 1) {
        if (tid < s) { sh[tid] += sh[tid + s]; sh[256 + tid] += sh[256 + tid + s]; }
        __syncthreads();
    }
    if (tid == 0) { partials[2 * blk] = sh[0]; partials[2 * blk + 1] = sh[256]; }
}

// Fixed-order final combine: bit-deterministic scalar output.
__global__ void final_kernel(const double* __restrict__ partials, float* __restrict__ out) {
    __shared__ double bmv[4];
    int t = threadIdx.x;
    if (t < 4) {
        double s = 0.0, c = 0.0;
        for (int i = 0; i < 8; ++i) {
            s += partials[2 * (t * 8 + i)];
            c += partials[2 * (t * 8 + i) + 1];
        }
        if (c < 1.0) c = 1.0;
        bmv[t] = s / (3.0 * c);
    }
    __syncthreads();
    if (t == 0) out[0] = (float)((bmv[0] + bmv[1] + bmv[2] + bmv[3]) * 0.25);
}

extern "C" void kernel_launch(void* const* d_in, const int* in_sizes, int n_in,
                              void* d_out, int out_size, void* d_ws, size_t ws_size,
                              hipStream_t stream) {
    const float* src = (const float*)d_in[0];
    const float* tgt = (const float*)d_in[1];
    float* out = (float*)d_out;

    unsigned* wsmin  = (unsigned*)d_ws;                                   // 128 KiB
    double* partials = (double*)((char*)d_ws + (size_t)BN * sizeof(unsigned)); // 512 B

    init_kernel<<<dim3(BN / 256), dim3(256), 0, stream>>>(wsmin);
    nn_min_kernel<<<dim3(NXBLK, NCHUNK), dim3(TPB), 0, stream>>>(src, tgt, wsmin);
    reduce_kernel<<<dim3(32), dim3(256), 0, stream>>>(src, wsmin, partials);
    final_kernel<<<dim3(1), dim3(64), 0, stream>>>(partials, out);
}